// Round 4
// baseline (132.321 us; speedup 1.0000x reference)
//
#include <hip/hip_runtime.h>

// Problem constants
#define NB   16
#define CIN  256
#define COUT 256
#define HH   32
#define WW   32
#define HW   1024           // 32*32
#define KK   9
#define CK   2304           // CIN*KK  (ordered k*256 + c, tap-major)

typedef __bf16 bf16x8 __attribute__((ext_vector_type(8)));
typedef float  f32x4  __attribute__((ext_vector_type(4)));

__device__ __forceinline__ unsigned short f2bf(float f) {
    unsigned int u = __float_as_uint(f);
    u += 0x7FFFu + ((u >> 16) & 1u);          // round-nearest-even
    return (unsigned short)(u >> 16);
}
__device__ __forceinline__ float bfhi(unsigned int u) {   // high bf16 -> f32
    return __uint_as_float(u & 0xFFFF0000u);
}
__device__ __forceinline__ float bflo(unsigned int u) {   // low bf16 -> f32
    return __uint_as_float(u << 16);
}

typedef const __attribute__((address_space(1))) void* gas_ptr;
typedef __attribute__((address_space(3))) void* las_ptr;

__device__ __forceinline__ void async16(const void* g, void* l) {
    __builtin_amdgcn_global_load_lds((gas_ptr)g, (las_ptr)l, 16, 0, 0);
}

// ---------------------------------------------------------------- wconv ----
// weight fp32 [O][C][3][3] -> bf16 [O][k*256+c]  (tap-major)
__global__ __launch_bounds__(256) void wconv_kernel(const float* __restrict__ w,
                                                    unsigned short* __restrict__ wbf) {
    __shared__ float ls[CK];
    const int o = blockIdx.x;
    const float* wo = w + (size_t)o * CK;
#pragma unroll
    for (int i = threadIdx.x; i < CK; i += 256) ls[i] = wo[i];
    __syncthreads();
    unsigned short* dst = wbf + (size_t)o * CK;
#pragma unroll
    for (int i = threadIdx.x; i < CK; i += 256) {
        int k = i >> 8, c = i & 255;
        dst[i] = f2bf(ls[c * KK + k]);        // bank stride 9: conflict-free
    }
}

// ------------------------------------------------------------------- xt ----
// x fp32 [n][c][hw] -> xtb bf16 [n][hw][c]   (64x64 LDS tile transpose)
__global__ __launch_bounds__(256) void xt_kernel(const float* __restrict__ x,
                                                 unsigned short* __restrict__ xtb) {
    __shared__ float ls[64][65];
    const int c0  = blockIdx.x * 64;
    const int hw0 = blockIdx.y * 64;
    const int n   = blockIdx.z;
    const int t   = threadIdx.x;
    {
        int c = t >> 2, q = t & 3;
        const float* base = x + ((size_t)(n * CIN + c0 + c)) * HW + hw0 + q * 16;
#pragma unroll
        for (int j = 0; j < 16; ++j) ls[c][q * 16 + j] = base[j];
    }
    __syncthreads();
    {
        int hw = t >> 2, seg = (t & 3) * 16;
        unsigned int dw[8];
#pragma unroll
        for (int j = 0; j < 8; ++j) {
            float f0 = ls[seg + 2 * j][hw];
            float f1 = ls[seg + 2 * j + 1][hw];
            dw[j] = (unsigned)f2bf(f0) | ((unsigned)f2bf(f1) << 16);
        }
        uint4* dst = (uint4*)(xtb + ((size_t)(n * HW + hw0 + hw)) * CIN + c0 + seg);
        dst[0] = *(uint4*)&dw[0];
        dst[1] = *(uint4*)&dw[4];
    }
}

// ---------------------------------------------------------------- fused ----
// Per block: out[0..255][hw0..hw0+63] for one image. BM=256, BN=64, BK=64.
// 512 threads / 8 waves, wave tile 32(o) x 64(hw), acc[2][4].
// B-tile built on the fly: 8 threads per hw; corner rows for the current tap
// (all 4 c0-steps) cached in 16 uint4 registers -> lerp -> swizzled ds_write.
// A staged via global_load_lds w/ XOR-swizzled source lanes.
// LDS layout: rows of 64 bf16 (128B = 8 chunks); LDS[row][j] = G[row][j^(row&7)].
__global__ __launch_bounds__(512, 2) void fused_kernel(const unsigned short* __restrict__ wbf,
                                                       const unsigned short* __restrict__ xtb,
                                                       const float* __restrict__ off,
                                                       float* __restrict__ out) {
    __shared__ unsigned short As[256 * 64];   // 32 KB
    __shared__ unsigned short Bs[64 * 64];    // 8 KB

    const int tid  = threadIdx.x;
    const int wv   = tid >> 6;                // 0..7  (M position, 32 rows each)
    const int lane = tid & 63;
    const int quad = lane >> 4;
    const int l15  = lane & 15;

    const int hw_local = tid >> 3;            // 0..63
    const int seg      = tid & 7;             // 8-channel segment within 64

    const int id  = blockIdx.x;
    const int hw0 = (id & 15) * 64;
    const int n   = id >> 4;

    const int hw = hw0 + hw_local;
    const int h  = hw >> 5, w = hw & 31;

    // A staging lane pattern (XOR swizzle encoded in source address)
    const int srow   = lane >> 3;
    const int schunk = (lane & 7) ^ (srow & 7);

    const uint4*  xb4  = (const uint4*)(xtb + (size_t)n * HW * CIN);
    const float2* offp = (const float2*)(off + ((size_t)n * HW + hw) * (2 * KK));

    f32x4 acc[2][4] = {};

    for (int tap = 0; tap < KK; ++tap) {
        // ---- per-(hw,tap) bilinear setup (8 threads/hw compute redundantly)
        float2 o = offp[tap];
        float py = (float)(h + tap / 3 - 1) + o.x;
        float px = (float)(w + tap % 3 - 1) + o.y;
        float y0f = floorf(py), x0f = floorf(px);
        float ly = py - y0f, lx = px - x0f;
        int y0 = (int)y0f, x0 = (int)x0f;

        float wg[4];
        int   ix[4];
#pragma unroll
        for (int c2 = 0; c2 < 4; ++c2) {
            int yy = y0 + (c2 >> 1);
            int xx = x0 + (c2 & 1);
            float wy = (c2 >> 1) ? ly : 1.0f - ly;
            float wx = (c2 & 1) ? lx : 1.0f - lx;
            bool v = (yy >= 0) && (yy < HH) && (xx >= 0) && (xx < WW);
            wg[c2] = v ? wy * wx : 0.0f;
            int yc = yy < 0 ? 0 : (yy > HH - 1 ? HH - 1 : yy);
            int xc = xx < 0 ? 0 : (xx > WW - 1 ? WW - 1 : xx);
            ix[c2] = yc * WW + xc;
        }

        // ---- load corner rows for ALL 4 c0-steps of this tap (16 uint4)
        uint4 cr[4][4];
#pragma unroll
        for (int c2 = 0; c2 < 4; ++c2) {
            const uint4* rp = xb4 + (size_t)ix[c2] * 32 + seg;
#pragma unroll
            for (int s = 0; s < 4; ++s) cr[c2][s] = rp[s * 8];
        }

#pragma unroll
        for (int s = 0; s < 4; ++s) {
            __syncthreads();                  // prior MFMA reads of LDS done

            // ---- stage A tile (256 x 64): 4 lds-dma per wave
            const int ckb = tap * 256 + s * 64;
#pragma unroll
            for (int j = 0; j < 4; ++j) {
                int rb = wv * 32 + j * 8;
                async16(wbf + (size_t)(rb + srow) * CK + ckb + schunk * 8,
                        &As[rb * 64]);
            }

            // ---- build my 8 channels of the B tile
            unsigned dw[4];
            {
                unsigned u0[4], u1[4], u2[4], u3[4];
                *(uint4*)u0 = cr[0][s]; *(uint4*)u1 = cr[1][s];
                *(uint4*)u2 = cr[2][s]; *(uint4*)u3 = cr[3][s];
#pragma unroll
                for (int d = 0; d < 4; ++d) {
                    float lo = wg[0] * bflo(u0[d]) + wg[1] * bflo(u1[d])
                             + wg[2] * bflo(u2[d]) + wg[3] * bflo(u3[d]);
                    float hi = wg[0] * bfhi(u0[d]) + wg[1] * bfhi(u1[d])
                             + wg[2] * bfhi(u2[d]) + wg[3] * bfhi(u3[d]);
                    dw[d] = (unsigned)f2bf(lo) | ((unsigned)f2bf(hi) << 16);
                }
            }
            *(uint4*)&Bs[hw_local * 64 + (seg ^ (hw_local & 7)) * 8] = *(uint4*)dw;

            __syncthreads();                  // drains lds-dma + ds_writes

            // ---- fragments + MFMA
            bf16x8 af[2][2], bfr[4][2];
#pragma unroll
            for (int mi = 0; mi < 2; ++mi)
#pragma unroll
                for (int hh = 0; hh < 2; ++hh) {
                    int row = wv * 32 + mi * 16 + l15;
                    int ch  = (hh * 4 + quad) ^ (row & 7);
                    af[mi][hh] = *(const bf16x8*)&As[row * 64 + ch * 8];
                }
#pragma unroll
            for (int ni = 0; ni < 4; ++ni)
#pragma unroll
                for (int hh = 0; hh < 2; ++hh) {
                    int row = ni * 16 + l15;
                    int ch  = (hh * 4 + quad) ^ (row & 7);
                    bfr[ni][hh] = *(const bf16x8*)&Bs[row * 64 + ch * 8];
                }
#pragma unroll
            for (int mi = 0; mi < 2; ++mi)
#pragma unroll
                for (int ni = 0; ni < 4; ++ni) {
                    acc[mi][ni] = __builtin_amdgcn_mfma_f32_16x16x32_bf16(af[mi][0], bfr[ni][0], acc[mi][ni], 0, 0, 0);
                    acc[mi][ni] = __builtin_amdgcn_mfma_f32_16x16x32_bf16(af[mi][1], bfr[ni][1], acc[mi][ni], 0, 0, 0);
                }
        }
    }

    // ---- epilogue: D layout col = lane&15, row = quad*4 + reg
    float* opnt = out + (size_t)n * COUT * HW + hw0;
#pragma unroll
    for (int mi = 0; mi < 2; ++mi)
#pragma unroll
        for (int ni = 0; ni < 4; ++ni) {
            int col = ni * 16 + l15;
#pragma unroll
            for (int rr = 0; rr < 4; ++rr) {
                int row = wv * 32 + mi * 16 + quad * 4 + rr;
                opnt[(size_t)row * HW + col] = acc[mi][ni][rr];
            }
        }
}

// --------------------------------------------------------------- launch ----
extern "C" void kernel_launch(void* const* d_in, const int* in_sizes, int n_in,
                              void* d_out, int out_size, void* d_ws, size_t ws_size,
                              hipStream_t stream) {
    const float* x   = (const float*)d_in[0];   // [16][256][32][32]
    const float* off = (const float*)d_in[1];   // [16][1024][18]
    const float* wt  = (const float*)d_in[2];   // [256][256][3][3]
    float* out = (float*)d_out;                 // [16][256][32][32]

    unsigned short* wbf = (unsigned short*)d_ws;                        // 1179648 B
    unsigned short* xtb = (unsigned short*)((char*)d_ws + 1179648);     // 8388608 B

    wconv_kernel<<<256, 256, 0, stream>>>(wt, wbf);
    xt_kernel<<<dim3(4, 16, 16), 256, 0, stream>>>(x, xtb);
    fused_kernel<<<256, 512, 0, stream>>>(wbf, xtb, off, out);
}

// Round 5
// 125.386 us; speedup vs baseline: 1.0553x; 1.0553x over previous
//
#include <hip/hip_runtime.h>

// Problem constants
#define NB   16
#define CIN  256
#define COUT 256
#define HH   32
#define WW   32
#define HW   1024           // 32*32
#define KK   9
#define CK   2304           // CIN*KK  (ordered k*256 + c, tap-major)

typedef __bf16 bf16x8 __attribute__((ext_vector_type(8)));
typedef float  f32x4  __attribute__((ext_vector_type(4)));

__device__ __forceinline__ unsigned short f2bf(float f) {
    unsigned int u = __float_as_uint(f);
    u += 0x7FFFu + ((u >> 16) & 1u);          // round-nearest-even
    return (unsigned short)(u >> 16);
}
__device__ __forceinline__ float bfhi(unsigned int u) {   // high bf16 -> f32
    return __uint_as_float(u & 0xFFFF0000u);
}
__device__ __forceinline__ float bflo(unsigned int u) {   // low bf16 -> f32
    return __uint_as_float(u << 16);
}

typedef const __attribute__((address_space(1))) void* gas_ptr;
typedef __attribute__((address_space(3))) void* las_ptr;

__device__ __forceinline__ void async16(const void* g, void* l) {
    __builtin_amdgcn_global_load_lds((gas_ptr)g, (las_ptr)l, 16, 0, 0);
}

// ---------------------------------------------------------------- wconv ----
// weight fp32 [O][C][3][3] -> bf16 [O][k*256+c]  (tap-major)
__global__ __launch_bounds__(256) void wconv_kernel(const float* __restrict__ w,
                                                    unsigned short* __restrict__ wbf) {
    __shared__ float ls[CK];
    const int o = blockIdx.x;
    const float* wo = w + (size_t)o * CK;
#pragma unroll
    for (int i = threadIdx.x; i < CK; i += 256) ls[i] = wo[i];
    __syncthreads();
    unsigned short* dst = wbf + (size_t)o * CK;
#pragma unroll
    for (int i = threadIdx.x; i < CK; i += 256) {
        int k = i >> 8, c = i & 255;
        dst[i] = f2bf(ls[c * KK + k]);        // bank stride 9: conflict-free
    }
}

// ------------------------------------------------------------------- xt ----
// x fp32 [n][c][hw] -> xtb bf16 [n][hw][c]   (64x64 LDS tile transpose)
__global__ __launch_bounds__(256) void xt_kernel(const float* __restrict__ x,
                                                 unsigned short* __restrict__ xtb) {
    __shared__ float ls[64][65];
    const int c0  = blockIdx.x * 64;
    const int hw0 = blockIdx.y * 64;
    const int n   = blockIdx.z;
    const int t   = threadIdx.x;
    {
        int c = t >> 2, q = t & 3;
        const float* base = x + ((size_t)(n * CIN + c0 + c)) * HW + hw0 + q * 16;
#pragma unroll
        for (int j = 0; j < 16; ++j) ls[c][q * 16 + j] = base[j];
    }
    __syncthreads();
    {
        int hw = t >> 2, seg = (t & 3) * 16;
        unsigned int dw[8];
#pragma unroll
        for (int j = 0; j < 8; ++j) {
            float f0 = ls[seg + 2 * j][hw];
            float f1 = ls[seg + 2 * j + 1][hw];
            dw[j] = (unsigned)f2bf(f0) | ((unsigned)f2bf(f1) << 16);
        }
        uint4* dst = (uint4*)(xtb + ((size_t)(n * HW + hw0 + hw)) * CIN + c0 + seg);
        dst[0] = *(uint4*)&dw[0];
        dst[1] = *(uint4*)&dw[4];
    }
}

// ---------------------------------------------------------------- fused ----
// Per block: out[0..255][hw0..hw0+63] for one image. BM=256, BN=64, BK=64.
// 512 threads / 8 waves, wave tile 32(o) x 64(hw).
// Single-barrier K-loop: fully double-buffered LDS (As[2] 64KB + Bs[2] 16KB);
// each step runs MFMA on buffer pb while staging step+1 into pb^1 (A via
// lds-DMA, B lerped from corners prefetched one step earlier) and prefetching
// corners for step+2. XCD-aware block decode: blockIdx%8 -> XCD, so each XCD
// owns 2 images (xtb slice 2MB + wbf 1.18MB resident in its 4MB L2).
__global__ __launch_bounds__(512, 2) void fused_kernel(const unsigned short* __restrict__ wbf,
                                                       const unsigned short* __restrict__ xtb,
                                                       const float* __restrict__ off,
                                                       float* __restrict__ out) {
    __shared__ unsigned short As[2][256 * 64];   // 64 KB
    __shared__ unsigned short Bs[2][64 * 64];    // 16 KB

    const int tid  = threadIdx.x;
    const int wv   = tid >> 6;                // 0..7  (M position, 32 rows each)
    const int lane = tid & 63;
    const int quad = lane >> 4;
    const int l15  = lane & 15;

    const int hw_local = tid >> 3;            // 0..63
    const int seg      = tid & 7;             // 8-channel segment within 64

    // XCD-aware decode (gfx950 dispatch: consecutive ids round-robin XCDs)
    const int id  = blockIdx.x;
    const int n   = ((id & 7) << 1) | ((id >> 3) & 1);
    const int hw0 = (id >> 4) * 64;

    const int hw = hw0 + hw_local;
    const int h  = hw >> 5, w = hw & 31;

    // A staging lane pattern (XOR swizzle encoded in source address)
    const int srow   = lane >> 3;
    const int schunk = (lane & 7) ^ (srow & 7);

    const uint4*  xb4  = (const uint4*)(xtb + (size_t)n * HW * CIN);
    const float2* offp = (const float2*)(off + ((size_t)n * HW + hw) * (2 * KK));

    f32x4 acc[2][4] = {};

    auto setup = [&](int tap, float wg[4], int ix[4]) {
        float2 o = offp[tap];
        float py = (float)(h + tap / 3 - 1) + o.x;
        float px = (float)(w + tap % 3 - 1) + o.y;
        float y0f = floorf(py), x0f = floorf(px);
        float ly = py - y0f, lx = px - x0f;
        int y0 = (int)y0f, x0 = (int)x0f;
#pragma unroll
        for (int c2 = 0; c2 < 4; ++c2) {
            int yy = y0 + (c2 >> 1);
            int xx = x0 + (c2 & 1);
            float wy = (c2 >> 1) ? ly : 1.0f - ly;
            float wx = (c2 & 1) ? lx : 1.0f - lx;
            bool v = (yy >= 0) && (yy < HH) && (xx >= 0) && (xx < WW);
            wg[c2] = v ? wy * wx : 0.0f;
            int yc = yy < 0 ? 0 : (yy > HH - 1 ? HH - 1 : yy);
            int xc = xx < 0 ? 0 : (xx > WW - 1 ? WW - 1 : xx);
            ix[c2] = yc * WW + xc;
        }
    };

    auto loadc = [&](uint4 cr[4], const int ix[4], int s) {
#pragma unroll
        for (int c2 = 0; c2 < 4; ++c2)
            cr[c2] = xb4[(size_t)ix[c2] * 32 + s * 8 + seg];
    };

    // stage step (A-DMA into As[nb] at ckb; lerp corners -> Bs[nb])
    auto build = [&](int nb, int ckb, const uint4 cr[4], const float wg[4]) {
        unsigned u0[4], u1[4], u2[4], u3[4];
        *(uint4*)u0 = cr[0]; *(uint4*)u1 = cr[1];
        *(uint4*)u2 = cr[2]; *(uint4*)u3 = cr[3];
        unsigned dw[4];
#pragma unroll
        for (int d = 0; d < 4; ++d) {
            float lo = wg[0] * bflo(u0[d]) + wg[1] * bflo(u1[d])
                     + wg[2] * bflo(u2[d]) + wg[3] * bflo(u3[d]);
            float hi = wg[0] * bfhi(u0[d]) + wg[1] * bfhi(u1[d])
                     + wg[2] * bfhi(u2[d]) + wg[3] * bfhi(u3[d]);
            dw[d] = (unsigned)f2bf(lo) | ((unsigned)f2bf(hi) << 16);
        }
        *(uint4*)&Bs[nb][hw_local * 64 + (seg ^ (hw_local & 7)) * 8] = *(uint4*)dw;
#pragma unroll
        for (int j = 0; j < 4; ++j) {
            int rb = wv * 32 + j * 8;
            async16(wbf + (size_t)(rb + srow) * CK + ckb + schunk * 8, &As[nb][rb * 64]);
        }
    };

    auto mfma_step = [&](int pb) {
        bf16x8 af[2][2], bfr[4][2];
#pragma unroll
        for (int mi = 0; mi < 2; ++mi)
#pragma unroll
            for (int hh = 0; hh < 2; ++hh) {
                int row = wv * 32 + mi * 16 + l15;
                int ch  = (hh * 4 + quad) ^ (row & 7);
                af[mi][hh] = *(const bf16x8*)&As[pb][row * 64 + ch * 8];
            }
#pragma unroll
        for (int ni = 0; ni < 4; ++ni)
#pragma unroll
            for (int hh = 0; hh < 2; ++hh) {
                int row = ni * 16 + l15;
                int ch  = (hh * 4 + quad) ^ (row & 7);
                bfr[ni][hh] = *(const bf16x8*)&Bs[pb][row * 64 + ch * 8];
            }
#pragma unroll
        for (int mi = 0; mi < 2; ++mi)
#pragma unroll
            for (int ni = 0; ni < 4; ++ni) {
                acc[mi][ni] = __builtin_amdgcn_mfma_f32_16x16x32_bf16(af[mi][0], bfr[ni][0], acc[mi][ni], 0, 0, 0);
                acc[mi][ni] = __builtin_amdgcn_mfma_f32_16x16x32_bf16(af[mi][1], bfr[ni][1], acc[mi][ni], 0, 0, 0);
            }
    };

    // ---- prologue: stage step (0,0) into buffer 0, prefetch (0,1)
    float wgc[4], wgn[4];
    int   ixc[4], ixn[4];
    uint4 crA[4], crB[4];

    setup(0, wgc, ixc);
    loadc(crA, ixc, 0);
    build(0, 0, crA, wgc);
    loadc(crB, ixc, 1);
    __syncthreads();

    // ---- main loop: 36 steps, one barrier each, buffers ping-pong (pb = s&1)
    for (int tap = 0; tap < 9; ++tap) {
        const int ckb = tap * 256;
        // s = 0: compute (tap,0) | stage (tap,1) | prefetch (tap,2)
        mfma_step(0);
        build(1, ckb + 64, crB, wgc);
        loadc(crA, ixc, 2);
        __syncthreads();
        // s = 1: compute (tap,1) | stage (tap,2) | prefetch (tap,3)
        mfma_step(1);
        build(0, ckb + 128, crA, wgc);
        loadc(crB, ixc, 3);
        __syncthreads();
        // s = 2: compute (tap,2) | stage (tap,3) | prefetch (tap+1,0)
        mfma_step(0);
        build(1, ckb + 192, crB, wgc);
        if (tap < 8) { setup(tap + 1, wgn, ixn); loadc(crA, ixn, 0); }
        __syncthreads();
        // s = 3: compute (tap,3) | stage (tap+1,0) | prefetch (tap+1,1)
        mfma_step(1);
        if (tap < 8) {
            build(0, ckb + 256, crA, wgn);
            loadc(crB, ixn, 1);
#pragma unroll
            for (int c2 = 0; c2 < 4; ++c2) { wgc[c2] = wgn[c2]; ixc[c2] = ixn[c2]; }
            __syncthreads();
        }
    }

    // ---- epilogue: D layout col = lane&15, row = quad*4 + reg
    float* opnt = out + (size_t)n * COUT * HW + hw0;
#pragma unroll
    for (int mi = 0; mi < 2; ++mi)
#pragma unroll
        for (int ni = 0; ni < 4; ++ni) {
            int col = ni * 16 + l15;
#pragma unroll
            for (int rr = 0; rr < 4; ++rr) {
                int row = wv * 32 + mi * 16 + quad * 4 + rr;
                opnt[(size_t)row * HW + col] = acc[mi][ni][rr];
            }
        }
}

// --------------------------------------------------------------- launch ----
extern "C" void kernel_launch(void* const* d_in, const int* in_sizes, int n_in,
                              void* d_out, int out_size, void* d_ws, size_t ws_size,
                              hipStream_t stream) {
    const float* x   = (const float*)d_in[0];   // [16][256][32][32]
    const float* off = (const float*)d_in[1];   // [16][1024][18]
    const float* wt  = (const float*)d_in[2];   // [256][256][3][3]
    float* out = (float*)d_out;                 // [16][256][32][32]

    unsigned short* wbf = (unsigned short*)d_ws;                        // 1179648 B
    unsigned short* xtb = (unsigned short*)((char*)d_ws + 1179648);     // 8388608 B

    wconv_kernel<<<256, 256, 0, stream>>>(wt, wbf);
    xt_kernel<<<dim3(4, 16, 16), 256, 0, stream>>>(x, xtb);
    fused_kernel<<<256, 512, 0, stream>>>(wbf, xtb, off, out);
}

// Round 6
// 122.303 us; speedup vs baseline: 1.0819x; 1.0252x over previous
//
#include <hip/hip_runtime.h>

// Problem constants
#define NB   16
#define CIN  256
#define COUT 256
#define HH   32
#define WW   32
#define HW   1024           // 32*32
#define KK   9
#define CK   2304           // CIN*KK  (ordered k*256 + c, tap-major)

typedef __bf16 bf16x8 __attribute__((ext_vector_type(8)));
typedef float  f32x4  __attribute__((ext_vector_type(4)));

__device__ __forceinline__ unsigned short f2bf(float f) {
    unsigned int u = __float_as_uint(f);
    u += 0x7FFFu + ((u >> 16) & 1u);          // round-nearest-even
    return (unsigned short)(u >> 16);
}
__device__ __forceinline__ float bfhi(unsigned int u) {   // high bf16 -> f32
    return __uint_as_float(u & 0xFFFF0000u);
}
__device__ __forceinline__ float bflo(unsigned int u) {   // low bf16 -> f32
    return __uint_as_float(u << 16);
}

typedef const __attribute__((address_space(1))) void* gas_ptr;
typedef __attribute__((address_space(3))) void* las_ptr;

__device__ __forceinline__ void async16(const void* g, void* l) {
    __builtin_amdgcn_global_load_lds((gas_ptr)g, (las_ptr)l, 16, 0, 0);
}

// ---------------------------------------------------------------- wconv ----
// weight fp32 [O][C][3][3] -> bf16 [O][k*256+c]  (tap-major)
__global__ __launch_bounds__(256) void wconv_kernel(const float* __restrict__ w,
                                                    unsigned short* __restrict__ wbf) {
    __shared__ float ls[CK];
    const int o = blockIdx.x;
    const float* wo = w + (size_t)o * CK;
#pragma unroll
    for (int i = threadIdx.x; i < CK; i += 256) ls[i] = wo[i];
    __syncthreads();
    unsigned short* dst = wbf + (size_t)o * CK;
#pragma unroll
    for (int i = threadIdx.x; i < CK; i += 256) {
        int k = i >> 8, c = i & 255;
        dst[i] = f2bf(ls[c * KK + k]);        // bank stride 9: conflict-free
    }
}

// ------------------------------------------------------------------- xt ----
// x fp32 [n][c][hw] -> xtb bf16 [n][hw][c]   (64x64 LDS tile transpose)
__global__ __launch_bounds__(256) void xt_kernel(const float* __restrict__ x,
                                                 unsigned short* __restrict__ xtb) {
    __shared__ float ls[64][65];
    const int c0  = blockIdx.x * 64;
    const int hw0 = blockIdx.y * 64;
    const int n   = blockIdx.z;
    const int t   = threadIdx.x;
    {
        int c = t >> 2, q = t & 3;
        const float4* base = (const float4*)(x + ((size_t)(n * CIN + c0 + c)) * HW + hw0 + q * 16);
#pragma unroll
        for (int j = 0; j < 4; ++j) {
            float4 v = base[j];
            ls[c][q * 16 + j * 4 + 0] = v.x;
            ls[c][q * 16 + j * 4 + 1] = v.y;
            ls[c][q * 16 + j * 4 + 2] = v.z;
            ls[c][q * 16 + j * 4 + 3] = v.w;
        }
    }
    __syncthreads();
    {
        int hw = t >> 2, seg = (t & 3) * 16;
        unsigned int dw[8];
#pragma unroll
        for (int j = 0; j < 8; ++j) {
            float f0 = ls[seg + 2 * j][hw];
            float f1 = ls[seg + 2 * j + 1][hw];
            dw[j] = (unsigned)f2bf(f0) | ((unsigned)f2bf(f1) << 16);
        }
        uint4* dst = (uint4*)(xtb + ((size_t)(n * HW + hw0 + hw)) * CIN + c0 + seg);
        dst[0] = *(uint4*)&dw[0];
        dst[1] = *(uint4*)&dw[4];
    }
}

// ---------------------------------------------------------------- fused ----
// Per block: out[0..255][hw0..hw0+63] for one image. BM=256, BN=64, BK=64.
// 512 threads / 8 waves, wave tile 32(o) x 64(hw).
// Single-barrier K-loop, double-buffered LDS. Step order (latency-hiding):
//   issue A-DMA(next) -> lerp+ds_write B(next) -> prefetch corners(next+1)
//   -> MFMA(cur) -> barrier.
// The DMA/ds_writes drain during the MFMA phase, so the barrier's
// vmcnt(0)/lgkmcnt(0) is nearly free. XCD-aware block decode keeps each
// image's xtb slice + wbf inside one XCD's L2.
__global__ __launch_bounds__(512, 2) void fused_kernel(const unsigned short* __restrict__ wbf,
                                                       const unsigned short* __restrict__ xtb,
                                                       const float* __restrict__ off,
                                                       float* __restrict__ out) {
    __shared__ unsigned short As[2][256 * 64];   // 64 KB
    __shared__ unsigned short Bs[2][64 * 64];    // 16 KB

    const int tid  = threadIdx.x;
    const int wv   = tid >> 6;                // 0..7  (M position, 32 rows each)
    const int lane = tid & 63;
    const int quad = lane >> 4;
    const int l15  = lane & 15;

    const int hw_local = tid >> 3;            // 0..63
    const int seg      = tid & 7;             // 8-channel segment within 64

    // XCD-aware decode (gfx950 dispatch: consecutive ids round-robin XCDs)
    const int id  = blockIdx.x;
    const int n   = ((id & 7) << 1) | ((id >> 3) & 1);
    const int hw0 = (id >> 4) * 64;

    const int hw = hw0 + hw_local;
    const int h  = hw >> 5, w = hw & 31;

    // A staging lane pattern (XOR swizzle encoded in source address)
    const int srow   = lane >> 3;
    const int schunk = (lane & 7) ^ (srow & 7);

    const uint4*  xb4  = (const uint4*)(xtb + (size_t)n * HW * CIN);
    const float2* offp = (const float2*)(off + ((size_t)n * HW + hw) * (2 * KK));

    f32x4 acc[2][4] = {};

    auto setup = [&](int tap, float wg[4], int ix[4]) {
        float2 o = offp[tap];
        float py = (float)(h + tap / 3 - 1) + o.x;
        float px = (float)(w + tap % 3 - 1) + o.y;
        float y0f = floorf(py), x0f = floorf(px);
        float ly = py - y0f, lx = px - x0f;
        int y0 = (int)y0f, x0 = (int)x0f;
#pragma unroll
        for (int c2 = 0; c2 < 4; ++c2) {
            int yy = y0 + (c2 >> 1);
            int xx = x0 + (c2 & 1);
            float wy = (c2 >> 1) ? ly : 1.0f - ly;
            float wx = (c2 & 1) ? lx : 1.0f - lx;
            bool v = (yy >= 0) && (yy < HH) && (xx >= 0) && (xx < WW);
            wg[c2] = v ? wy * wx : 0.0f;
            int yc = yy < 0 ? 0 : (yy > HH - 1 ? HH - 1 : yy);
            int xc = xx < 0 ? 0 : (xx > WW - 1 ? WW - 1 : xx);
            ix[c2] = yc * WW + xc;
        }
    };

    auto loadc = [&](uint4 cr[4], const int ix[4], int s) {
#pragma unroll
        for (int c2 = 0; c2 < 4; ++c2)
            cr[c2] = xb4[(size_t)ix[c2] * 32 + s * 8 + seg];
    };

    // stage step: A-DMA first (in flight during lerp+MFMA), then lerp -> Bs
    auto build = [&](int nb, int ckb, const uint4 cr[4], const float wg[4]) {
#pragma unroll
        for (int j = 0; j < 4; ++j) {
            int rb = wv * 32 + j * 8;
            async16(wbf + (size_t)(rb + srow) * CK + ckb + schunk * 8, &As[nb][rb * 64]);
        }
        unsigned u0[4], u1[4], u2[4], u3[4];
        *(uint4*)u0 = cr[0]; *(uint4*)u1 = cr[1];
        *(uint4*)u2 = cr[2]; *(uint4*)u3 = cr[3];
        unsigned dw[4];
#pragma unroll
        for (int d = 0; d < 4; ++d) {
            float lo = wg[0] * bflo(u0[d]) + wg[1] * bflo(u1[d])
                     + wg[2] * bflo(u2[d]) + wg[3] * bflo(u3[d]);
            float hi = wg[0] * bfhi(u0[d]) + wg[1] * bfhi(u1[d])
                     + wg[2] * bfhi(u2[d]) + wg[3] * bfhi(u3[d]);
            dw[d] = (unsigned)f2bf(lo) | ((unsigned)f2bf(hi) << 16);
        }
        *(uint4*)&Bs[nb][hw_local * 64 + (seg ^ (hw_local & 7)) * 8] = *(uint4*)dw;
    };

    auto mfma_step = [&](int pb) {
        bf16x8 af[2][2], bfr[4][2];
#pragma unroll
        for (int mi = 0; mi < 2; ++mi)
#pragma unroll
            for (int hh = 0; hh < 2; ++hh) {
                int row = wv * 32 + mi * 16 + l15;
                int ch  = (hh * 4 + quad) ^ (row & 7);
                af[mi][hh] = *(const bf16x8*)&As[pb][row * 64 + ch * 8];
            }
#pragma unroll
        for (int ni = 0; ni < 4; ++ni)
#pragma unroll
            for (int hh = 0; hh < 2; ++hh) {
                int row = ni * 16 + l15;
                int ch  = (hh * 4 + quad) ^ (row & 7);
                bfr[ni][hh] = *(const bf16x8*)&Bs[pb][row * 64 + ch * 8];
            }
#pragma unroll
        for (int mi = 0; mi < 2; ++mi)
#pragma unroll
            for (int ni = 0; ni < 4; ++ni) {
                acc[mi][ni] = __builtin_amdgcn_mfma_f32_16x16x32_bf16(af[mi][0], bfr[ni][0], acc[mi][ni], 0, 0, 0);
                acc[mi][ni] = __builtin_amdgcn_mfma_f32_16x16x32_bf16(af[mi][1], bfr[ni][1], acc[mi][ni], 0, 0, 0);
            }
    };

    // ---- prologue: stage step (0,0) into buffer 0, prefetch (0,1)
    float wgc[4], wgn[4];
    int   ixc[4], ixn[4];
    uint4 crA[4], crB[4];

    setup(0, wgc, ixc);
    loadc(crA, ixc, 0);
    build(0, 0, crA, wgc);
    loadc(crB, ixc, 1);
    __syncthreads();

    // ---- main loop: 36 steps; stage-next BEFORE compute-current each step
    for (int tap = 0; tap < 9; ++tap) {
        const int ckb = tap * 256;
        // step s=0: stage (tap,1)->buf1 | prefetch (tap,2) | compute buf0
        build(1, ckb + 64, crB, wgc);
        loadc(crA, ixc, 2);
        mfma_step(0);
        __syncthreads();
        // step s=1: stage (tap,2)->buf0 | prefetch (tap,3) | compute buf1
        build(0, ckb + 128, crA, wgc);
        loadc(crB, ixc, 3);
        mfma_step(1);
        __syncthreads();
        // step s=2: stage (tap,3)->buf1 | prefetch (tap+1,0) | compute buf0
        build(1, ckb + 192, crB, wgc);
        if (tap < 8) { setup(tap + 1, wgn, ixn); loadc(crA, ixn, 0); }
        mfma_step(0);
        __syncthreads();
        // step s=3: stage (tap+1,0)->buf0 | prefetch (tap+1,1) | compute buf1
        if (tap < 8) {
            build(0, ckb + 256, crA, wgn);
            loadc(crB, ixn, 1);
#pragma unroll
            for (int c2 = 0; c2 < 4; ++c2) { wgc[c2] = wgn[c2]; ixc[c2] = ixn[c2]; }
            mfma_step(1);
            __syncthreads();
        } else {
            mfma_step(1);
        }
    }

    // ---- epilogue: D layout col = lane&15, row = quad*4 + reg
    float* opnt = out + (size_t)n * COUT * HW + hw0;
#pragma unroll
    for (int mi = 0; mi < 2; ++mi)
#pragma unroll
        for (int ni = 0; ni < 4; ++ni) {
            int col = ni * 16 + l15;
#pragma unroll
            for (int rr = 0; rr < 4; ++rr) {
                int row = wv * 32 + mi * 16 + quad * 4 + rr;
                opnt[(size_t)row * HW + col] = acc[mi][ni][rr];
            }
        }
}

// --------------------------------------------------------------- launch ----
extern "C" void kernel_launch(void* const* d_in, const int* in_sizes, int n_in,
                              void* d_out, int out_size, void* d_ws, size_t ws_size,
                              hipStream_t stream) {
    const float* x   = (const float*)d_in[0];   // [16][256][32][32]
    const float* off = (const float*)d_in[1];   // [16][1024][18]
    const float* wt  = (const float*)d_in[2];   // [256][256][3][3]
    float* out = (float*)d_out;                 // [16][256][32][32]

    unsigned short* wbf = (unsigned short*)d_ws;                        // 1179648 B
    unsigned short* xtb = (unsigned short*)((char*)d_ws + 1179648);     // 8388608 B

    wconv_kernel<<<256, 256, 0, stream>>>(wt, wbf);
    xt_kernel<<<dim3(4, 16, 16), 256, 0, stream>>>(x, xtb);
    fused_kernel<<<256, 512, 0, stream>>>(wbf, xtb, off, out);
}